// Round 1
// baseline (366.245 us; speedup 1.0000x reference)
//
#include <hip/hip_runtime.h>
#include <stdint.h>

typedef __attribute__((ext_vector_type(8))) short short8;
typedef __attribute__((ext_vector_type(8))) unsigned short u16x8;
typedef __attribute__((ext_vector_type(4))) float f32x4;

#define DEV __device__ __forceinline__

DEV float bf2f(unsigned short v) {
    union { unsigned int u; float f; } c;
    c.u = ((unsigned int)v) << 16;
    return c.f;
}
DEV unsigned short f2bf(float f) {
    union { float f; unsigned int u; } c;
    c.f = f;
    unsigned int x = c.u;
    x += 0x7fffu + ((x >> 16) & 1u);   // round-to-nearest-even
    return (unsigned short)(x >> 16);
}

// ---------------------------------------------------------------------------
// K1: embedding gather + FM first/second order + write deep (bf16)
// block (64,4): lane = d (0..63), 4 batch rows per block
// ---------------------------------------------------------------------------
__global__ __launch_bounds__(256) void embed_fm(
    const int* __restrict__ cat, const float* __restrict__ cont,
    const float* __restrict__ bias,
    const float* __restrict__ t1c, const float* __restrict__ t2c,
    const float* __restrict__ t1x, const float* __restrict__ t2x,
    unsigned short* __restrict__ deep, float* __restrict__ fm)
{
    int row = blockIdx.x * 4 + threadIdx.y;
    int d = threadIdx.x;
    const int* crow = cat + row * 26;
    const float* xrow = cont + row * 13;
    unsigned short* drow = deep + (size_t)row * 2496;

    float s = 0.f, ss = 0.f;
    #pragma unroll
    for (int f = 0; f < 26; ++f) {
        int idx = crow[f];                                 // broadcast load
        float e = t2c[((size_t)f * 100000 + idx) * 64 + d]; // coalesced 256B row
        s += e; ss += e * e;
        drow[f * 64 + d] = f2bf(e);
    }
    #pragma unroll
    for (int f = 0; f < 13; ++f) {
        float x = xrow[f];
        float e = t2x[f * 64 + d] * x;
        s += e; ss += e * e;
        drow[(26 + f) * 64 + d] = f2bf(e);
    }
    // fm_second contribution per lane + first-order terms on lanes 0..25 / 0..12
    float val = 0.5f * (s * s - ss);
    if (d < 26) val += t1c[(size_t)d * 100000 + crow[d]];
    if (d < 13) val += t1x[d] * xrow[d];
    #pragma unroll
    for (int off = 32; off; off >>= 1) val += __shfl_xor(val, off);
    if (d == 0) fm[row] = bias[0] + val;
}

// ---------------------------------------------------------------------------
// Transpose + fp32->bf16 cast: in[R][C] f32 -> out[C][R] bf16. block (32,8).
// ---------------------------------------------------------------------------
__global__ __launch_bounds__(256) void transpose_cast(
    const float* __restrict__ in, unsigned short* __restrict__ out, int R, int C)
{
    __shared__ float tile[32][33];
    int c0 = blockIdx.x * 32, r0 = blockIdx.y * 32;
    int tx = threadIdx.x, ty = threadIdx.y;
    #pragma unroll
    for (int i = 0; i < 4; ++i)
        tile[ty + i * 8][tx] = in[(size_t)(r0 + ty + i * 8) * C + c0 + tx];
    __syncthreads();
    #pragma unroll
    for (int i = 0; i < 4; ++i)
        out[(size_t)(c0 + ty + i * 8) * R + r0 + tx] = f2bf(tile[tx][ty + i * 8]);
}

// ---------------------------------------------------------------------------
// bf16 GEMM: C[M,N] = A[M,K] * Bt[N,K]^T   (m97 structure: 128x128 tile, BK=64,
// 4 waves each computing 64x64 via 4x4 frags of mfma_f32_16x16x32_bf16,
// global_load_lds width-16 staging, single-buffered)
// M,N multiples of 128; K multiple of 64.
// ---------------------------------------------------------------------------
__global__ __launch_bounds__(256) void gemm_bf16(
    const unsigned short* __restrict__ A,
    const unsigned short* __restrict__ Bt,
    unsigned short* __restrict__ C,
    int M, int N, int K)
{
    __shared__ unsigned short As[128 * 64];
    __shared__ unsigned short Bs[128 * 64];
    const int nbn = N >> 7;
    const int bm = blockIdx.x / nbn;
    const int bn = blockIdx.x % nbn;
    const int tid = threadIdx.x;
    const int lane = tid & 63;
    const int wave = tid >> 6;
    const int wr = (wave >> 1) << 6;   // wave row offset in tile
    const int wc = (wave & 1) << 6;    // wave col offset in tile

    // staging: each thread covers 16B = 8 bf16; 256 thr * 16B = 32 rows x 64k
    const unsigned short* Ab = A + (size_t)(bm * 128 + (tid >> 3)) * K + (tid & 7) * 8;
    const unsigned short* Bb = Bt + (size_t)(bn * 128 + (tid >> 3)) * K + (tid & 7) * 8;
    unsigned short* Asl = &As[tid * 8];
    unsigned short* Bsl = &Bs[tid * 8];

    f32x4 acc[4][4];
    const f32x4 zero = {0.f, 0.f, 0.f, 0.f};
    #pragma unroll
    for (int m = 0; m < 4; ++m)
        #pragma unroll
        for (int n = 0; n < 4; ++n) acc[m][n] = zero;

    const int frow = lane & 15;          // A row / B col within fragment
    const int fk = (lane >> 4) * 8;      // k sub-offset

    for (int kt = 0; kt < K; kt += 64) {
        #pragma unroll
        for (int i = 0; i < 4; ++i) {
            __builtin_amdgcn_global_load_lds(
                (const __attribute__((address_space(1))) void*)(Ab + (size_t)(i * 32) * K + kt),
                (__attribute__((address_space(3))) void*)(Asl + i * 2048), 16, 0, 0);
            __builtin_amdgcn_global_load_lds(
                (const __attribute__((address_space(1))) void*)(Bb + (size_t)(i * 32) * K + kt),
                (__attribute__((address_space(3))) void*)(Bsl + i * 2048), 16, 0, 0);
        }
        __syncthreads();   // compiler drains vmcnt before barrier
        #pragma unroll
        for (int kk = 0; kk < 64; kk += 32) {
            short8 af[4], bfv[4];
            #pragma unroll
            for (int m = 0; m < 4; ++m)
                af[m] = *(const short8*)&As[(wr + m * 16 + frow) * 64 + kk + fk];
            #pragma unroll
            for (int n = 0; n < 4; ++n)
                bfv[n] = *(const short8*)&Bs[(wc + n * 16 + frow) * 64 + kk + fk];
            #pragma unroll
            for (int m = 0; m < 4; ++m)
                #pragma unroll
                for (int n = 0; n < 4; ++n)
                    acc[m][n] = __builtin_amdgcn_mfma_f32_16x16x32_bf16(
                        af[m], bfv[n], acc[m][n], 0, 0, 0);
        }
        __syncthreads();
    }

    // C/D layout: col = lane&15, row = (lane>>4)*4 + reg
    const int row0 = bm * 128 + wr + (lane >> 4) * 4;
    const int col0 = bn * 128 + wc + (lane & 15);
    #pragma unroll
    for (int m = 0; m < 4; ++m)
        #pragma unroll
        for (int n = 0; n < 4; ++n)
            #pragma unroll
            for (int r = 0; r < 4; ++r)
                C[(size_t)(row0 + m * 16 + r) * N + col0 + n * 16] = f2bf(acc[m][n][r]);
}

// ---------------------------------------------------------------------------
// Per-column sum / sum-of-squares over rows (bf16 input, fp32 atomics).
// blockDim.x = cols/4 (each thread owns 4 consecutive cols).
// ---------------------------------------------------------------------------
__global__ void col_stats(const unsigned short* __restrict__ z, int cols,
                          int rows_per_block,
                          float* __restrict__ sums, float* __restrict__ sqs)
{
    int c = threadIdx.x * 4;
    size_t r0 = (size_t)blockIdx.x * rows_per_block;
    float s0 = 0, s1 = 0, s2 = 0, s3 = 0, q0 = 0, q1 = 0, q2 = 0, q3 = 0;
    for (int r = 0; r < rows_per_block; ++r) {
        ushort4 u = *(const ushort4*)&z[(r0 + r) * cols + c];
        float x0 = bf2f(u.x), x1 = bf2f(u.y), x2 = bf2f(u.z), x3 = bf2f(u.w);
        s0 += x0; s1 += x1; s2 += x2; s3 += x3;
        q0 += x0 * x0; q1 += x1 * x1; q2 += x2 * x2; q3 += x3 * x3;
    }
    atomicAdd(&sums[c + 0], s0); atomicAdd(&sums[c + 1], s1);
    atomicAdd(&sums[c + 2], s2); atomicAdd(&sums[c + 3], s3);
    atomicAdd(&sqs[c + 0], q0); atomicAdd(&sqs[c + 1], q1);
    atomicAdd(&sqs[c + 2], q2); atomicAdd(&sqs[c + 3], q3);
}

// scale/shift per column: a = g*rsqrt(var+eps), b = be - mu*a   (b1/b2 cancel)
__global__ void bn_finalize(const float* __restrict__ sums, const float* __restrict__ sqs,
                            const float* __restrict__ g, const float* __restrict__ be,
                            int cols, float invB,
                            float* __restrict__ a, float* __restrict__ b)
{
    int c = blockIdx.x * 256 + threadIdx.x;
    if (c >= cols) return;
    float mu = sums[c] * invB;
    float var = sqs[c] * invB - mu * mu;
    float sc = g[c] * rsqrtf(var + 1e-5f);
    a[c] = sc;
    b[c] = be[c] - mu * sc;
}

// h = bf16(relu(a[c]*z + b[c])), 8 elems / thread
__global__ __launch_bounds__(256) void bn_relu_cast(
    const unsigned short* __restrict__ z, const float* __restrict__ a,
    const float* __restrict__ b, unsigned short* __restrict__ h,
    int cols, size_t n8)
{
    size_t id = (size_t)blockIdx.x * blockDim.x + threadIdx.x;
    if (id >= n8) return;
    size_t base = id * 8;
    int c0 = (int)(base % cols);
    u16x8 u = *(const u16x8*)&z[base];
    u16x8 o;
    #pragma unroll
    for (int j = 0; j < 8; ++j) {
        float x = a[c0 + j] * bf2f(u[j]) + b[c0 + j];
        o[j] = f2bf(fmaxf(x, 0.f));
    }
    *(u16x8*)&h[base] = o;
}

// ---------------------------------------------------------------------------
// Final: BN2 + ReLU + dot(W3) + b3 + fm -> sigmoid -> [1-p, p]
// block (64,4): one wave per row, lane owns 8 of 512 cols
// ---------------------------------------------------------------------------
__global__ __launch_bounds__(256) void final_k(
    const unsigned short* __restrict__ z2, const float* __restrict__ a2,
    const float* __restrict__ b2, const float* __restrict__ W3,
    const float* __restrict__ b3, const float* __restrict__ fm,
    float* __restrict__ out)
{
    int row = blockIdx.x * 4 + threadIdx.y;
    int lane = threadIdx.x;
    int c = lane * 8;
    u16x8 u = *(const u16x8*)&z2[(size_t)row * 512 + c];
    float dot = 0.f;
    #pragma unroll
    for (int j = 0; j < 8; ++j) {
        float x = a2[c + j] * bf2f(u[j]) + b2[c + j];
        dot += fmaxf(x, 0.f) * W3[c + j];
    }
    #pragma unroll
    for (int off = 32; off; off >>= 1) dot += __shfl_xor(dot, off);
    if (lane == 0) {
        float logit = fm[row] + dot + b3[0];
        float p = 1.f / (1.f + expf(-logit));
        out[row * 2 + 0] = 1.f - p;
        out[row * 2 + 1] = p;
    }
}

// ---------------------------------------------------------------------------
extern "C" void kernel_launch(void* const* d_in, const int* in_sizes, int n_in,
                              void* d_out, int out_size, void* d_ws, size_t ws_size,
                              hipStream_t stream)
{
    const int*   cat  = (const int*)d_in[0];
    const float* cont = (const float*)d_in[1];
    const float* bias = (const float*)d_in[2];
    const float* t1c  = (const float*)d_in[3];
    const float* t2c  = (const float*)d_in[4];
    const float* t1x  = (const float*)d_in[5];
    const float* t2x  = (const float*)d_in[6];
    const float* W1   = (const float*)d_in[7];
    // d_in[8] = b1: cancels under training-mode BN
    const float* g1   = (const float*)d_in[9];
    const float* be1  = (const float*)d_in[10];
    const float* W2   = (const float*)d_in[11];
    // d_in[12] = b2: cancels
    const float* g2   = (const float*)d_in[13];
    const float* be2  = (const float*)d_in[14];
    const float* W3   = (const float*)d_in[15];
    const float* b3   = (const float*)d_in[16];
    float* out = (float*)d_out;

    const int B = 16384, IN_DIM = 2496, H1 = 1024, H2 = 512;

    uint8_t* p = (uint8_t*)d_ws;
    auto carve = [&](size_t bytes) {
        uint8_t* r = p;
        p += (bytes + 255) & ~(size_t)255;
        return r;
    };
    unsigned short* deep = (unsigned short*)carve((size_t)B * IN_DIM * 2); // 81.8 MB
    unsigned short* w1t  = (unsigned short*)carve((size_t)H1 * IN_DIM * 2);
    unsigned short* w2t  = (unsigned short*)carve((size_t)H2 * H1 * 2);
    unsigned short* z1   = (unsigned short*)carve((size_t)B * H1 * 2);
    unsigned short* h1   = (unsigned short*)carve((size_t)B * H1 * 2);
    unsigned short* z2   = (unsigned short*)carve((size_t)B * H2 * 2);
    float* fm    = (float*)carve((size_t)B * 4);
    float* stats = (float*)carve((size_t)(H1 * 2 + H2 * 2) * 4);
    float* sums1 = stats, *sqs1 = stats + H1, *sums2 = stats + 2 * H1, *sqs2 = stats + 2 * H1 + H2;
    float* a1  = (float*)carve(H1 * 4);
    float* b1c = (float*)carve(H1 * 4);
    float* a2  = (float*)carve(H2 * 4);
    float* b2c = (float*)carve(H2 * 4);

    hipMemsetAsync(stats, 0, (size_t)(H1 * 2 + H2 * 2) * 4, stream);

    dim3 tb(32, 8);
    transpose_cast<<<dim3(H1 / 32, IN_DIM / 32), tb, 0, stream>>>(W1, w1t, IN_DIM, H1);
    transpose_cast<<<dim3(H2 / 32, H1 / 32), tb, 0, stream>>>(W2, w2t, H1, H2);

    embed_fm<<<B / 4, dim3(64, 4), 0, stream>>>(cat, cont, bias, t1c, t2c, t1x, t2x, deep, fm);

    gemm_bf16<<<(B / 128) * (H1 / 128), 256, 0, stream>>>(deep, w1t, z1, B, H1, IN_DIM);

    col_stats<<<128, H1 / 4, 0, stream>>>(z1, H1, B / 128, sums1, sqs1);
    bn_finalize<<<(H1 + 255) / 256, 256, 0, stream>>>(sums1, sqs1, g1, be1, H1, 1.f / B, a1, b1c);
    bn_relu_cast<<<(int)(((size_t)B * H1 / 8 + 255) / 256), 256, 0, stream>>>(
        z1, a1, b1c, h1, H1, (size_t)B * H1 / 8);

    gemm_bf16<<<(B / 128) * (H2 / 128), 256, 0, stream>>>(h1, w2t, z2, B, H2, H1);

    col_stats<<<128, H2 / 4, 0, stream>>>(z2, H2, B / 128, sums2, sqs2);
    bn_finalize<<<(H2 + 255) / 256, 256, 0, stream>>>(sums2, sqs2, g2, be2, H2, 1.f / B, a2, b2c);

    final_k<<<B / 4, dim3(64, 4), 0, stream>>>(z2, a2, b2c, W3, b3, fm, out);
}

// Round 2
// 273.476 us; speedup vs baseline: 1.3392x; 1.3392x over previous
//
#include <hip/hip_runtime.h>
#include <stdint.h>

typedef __attribute__((ext_vector_type(8))) short short8;
typedef __attribute__((ext_vector_type(8))) unsigned short u16x8;
typedef __attribute__((ext_vector_type(4))) float f32x4;

#define DEV __device__ __forceinline__

DEV float bf2f(unsigned short v) {
    union { unsigned int u; float f; } c;
    c.u = ((unsigned int)v) << 16;
    return c.f;
}
DEV unsigned short f2bf(float f) {
    union { float f; unsigned int u; } c;
    c.f = f;
    unsigned int x = c.u;
    x += 0x7fffu + ((x >> 16) & 1u);   // round-to-nearest-even
    return (unsigned short)(x >> 16);
}

// ---------------------------------------------------------------------------
// K1: embedding gather + FM first/second order + write deep (bf16, K-padded)
// block (64,4): lane = d (0..63), 4 batch rows per block.
// Rows staged in LDS, then written with 16B/lane coalesced stores.
// ---------------------------------------------------------------------------
__global__ __launch_bounds__(256) void embed_fm(
    const int* __restrict__ cat, const float* __restrict__ cont,
    const float* __restrict__ bias,
    const float* __restrict__ t1c, const float* __restrict__ t2c,
    const float* __restrict__ t1x, const float* __restrict__ t2x,
    unsigned short* __restrict__ deep, float* __restrict__ fm)
{
    __shared__ unsigned short rowbuf[4][2560];   // 20 KiB
    const int ty = threadIdx.y;
    const int row = blockIdx.x * 4 + ty;
    const int d = threadIdx.x;
    const int* crow = cat + row * 26;
    const float* xrow = cont + row * 13;

    float s = 0.f, ss = 0.f;
    #pragma unroll
    for (int f = 0; f < 26; ++f) {
        int idx = crow[f];                                  // broadcast load
        float e = t2c[((size_t)f * 100000 + idx) * 64 + d]; // coalesced 256B row
        s += e; ss += e * e;
        rowbuf[ty][f * 64 + d] = f2bf(e);
    }
    #pragma unroll
    for (int f = 0; f < 13; ++f) {
        float x = xrow[f];
        float e = t2x[f * 64 + d] * x;
        s += e; ss += e * e;
        rowbuf[ty][(26 + f) * 64 + d] = f2bf(e);
    }
    rowbuf[ty][2496 + d] = 0;   // zero K-pad (2496..2559)

    float val = 0.5f * (s * s - ss);
    if (d < 26) val += t1c[(size_t)d * 100000 + crow[d]];
    if (d < 13) val += t1x[d] * xrow[d];
    #pragma unroll
    for (int off = 32; off; off >>= 1) val += __shfl_xor(val, off);
    if (d == 0) fm[row] = bias[0] + val;

    __syncthreads();
    // cooperative coalesced store: 4 rows x 2560 bf16 = 10240 elems = 5 x (256thr x 8)
    const int tid = ty * 64 + d;
    const unsigned short* src = &rowbuf[0][0];
    unsigned short* dst = deep + (size_t)(blockIdx.x * 4) * 2560;
    #pragma unroll
    for (int it = 0; it < 5; ++it)
        *(u16x8*)(dst + it * 2048 + tid * 8) = *(const u16x8*)(src + it * 2048 + tid * 8);
}

// ---------------------------------------------------------------------------
// Transpose + fp32->bf16 cast with K-padding: in[R][C] f32 -> out[C][Kpad] bf16
// (rows R..Kpad-1 of the output's second dim are zero-filled). block (32,8).
// ---------------------------------------------------------------------------
__global__ __launch_bounds__(256) void transpose_cast(
    const float* __restrict__ in, unsigned short* __restrict__ out,
    int R, int C, int Kpad)
{
    __shared__ float tile[32][33];
    int c0 = blockIdx.x * 32, r0 = blockIdx.y * 32;
    int tx = threadIdx.x, ty = threadIdx.y;
    #pragma unroll
    for (int i = 0; i < 4; ++i) {
        int r = r0 + ty + i * 8;
        tile[ty + i * 8][tx] = (r < R) ? in[(size_t)r * C + c0 + tx] : 0.f;
    }
    __syncthreads();
    #pragma unroll
    for (int i = 0; i < 4; ++i)
        out[(size_t)(c0 + ty + i * 8) * Kpad + r0 + tx] = f2bf(tile[tx][ty + i * 8]);
}

// ---------------------------------------------------------------------------
// 256x256-tile 8-wave bf16 GEMM with 4-phase counted-vmcnt pipeline + LDS XOR
// swizzle + setprio, fused per-column sum/sumsq epilogue (for BatchNorm).
// C[M,N] = A[M,K] * Bt[N,K]^T.  M%256==0, N%256==0, K%64==0, K/64 >= 2.
//
// LDS: 2 buffers x (A 256x64 | B 256x64) bf16 = 128 KiB. Swizzle: logical
// (r, kchunk c) stored at elem r*64 + 8*(c ^ (r&7))  (involution, 16B-chunks).
// Staging uses global_load_lds (linear LDS dest) with pre-swizzled global src.
// Pipeline: tile t+2's A/B staged into buf[t&1] during tile t's phases p3/p1
// (regions proven consumed + barrier-separated); end-of-tile wait is
// s_waitcnt vmcnt(8) so 8 loads stay in flight across the barrier (T4).
// ---------------------------------------------------------------------------
__global__ __launch_bounds__(512, 2) void gemm256(
    const unsigned short* __restrict__ A,
    const unsigned short* __restrict__ Bt,
    unsigned short* __restrict__ C,
    float* __restrict__ sums, float* __restrict__ sqs,
    int M, int N, int K)
{
    __shared__ unsigned short lds[2][32768];   // [buf][A:0..16384 | B:16384..32768]
    const int tid = threadIdx.x;
    const int lane = tid & 63, wid = tid >> 6;
    const int wrow = wid >> 2, wcol = wid & 3;
    const int nbn = N >> 8;
    const int bm = blockIdx.x / nbn, bn = blockIdx.x % nbn;
    const int NT = K >> 6;

    // ---- staging addresses (pre-swizzled global source) ----
    const int srow = tid >> 3;                       // 0..63
    const int skc  = (tid & 7) ^ (srow & 7);         // swizzled k-chunk
    const unsigned short* Asrc = A + (size_t)(bm * 256 + srow) * K + skc * 8;
    const unsigned short* Bsrc = Bt + (size_t)(bn * 256 + srow) * K + skc * 8;

    #define STAGE_A(kt, b)                                                        \
        _Pragma("unroll")                                                         \
        for (int i_ = 0; i_ < 4; ++i_)                                            \
            __builtin_amdgcn_global_load_lds(                                     \
                (const __attribute__((address_space(1))) void*)(Asrc + (size_t)(i_ * 64) * K + (kt)), \
                (__attribute__((address_space(3))) void*)(&lds[b][tid * 8 + i_ * 4096]), 16, 0, 0);
    #define STAGE_B(kt, b)                                                        \
        _Pragma("unroll")                                                         \
        for (int i_ = 0; i_ < 4; ++i_)                                            \
            __builtin_amdgcn_global_load_lds(                                     \
                (const __attribute__((address_space(1))) void*)(Bsrc + (size_t)(i_ * 64) * K + (kt)), \
                (__attribute__((address_space(3))) void*)(&lds[b][16384 + tid * 8 + i_ * 4096]), 16, 0, 0);

    // ---- fragment read offsets (swizzled) ----
    const int l15 = lane & 15, l7 = lane & 7, lhi = lane >> 4;
    const int xo0 = 8 * (lhi ^ l7);          // kk=0 chunk offset (elems)
    const int xo1 = 8 * ((lhi + 4) ^ l7);    // kk=1 (k=32..63)
    const int aRow = wrow * 128 + l15;       // + mf*16
    const int bRow = wcol * 64 + l15;        // + nf*16

    f32x4 acc[8][4];
    #pragma unroll
    for (int m = 0; m < 8; ++m)
        #pragma unroll
        for (int n = 0; n < 4; ++n) acc[m][n] = (f32x4){0.f, 0.f, 0.f, 0.f};

    // ---- prologue: stage tiles 0 and 1, wait for tile 0 (vmcnt(8)) ----
    STAGE_A(0, 0); STAGE_B(0, 0);
    STAGE_A(64, 1); STAGE_B(64, 1);
    asm volatile("s_waitcnt vmcnt(8)" ::: "memory");
    __syncthreads();

    for (int t = 0; t < NT; ++t) {
        const int cb = t & 1;
        const unsigned short* base = &lds[cb][0];
        const int ktp = (t + 2) << 6;
        const bool pf = (t + 2) < NT;

        short8 a[4][2], bfr[4][2];
        // ---- p0: read A-mh0 (8) + all B (8); MFMA Q(0, nh0) ----
        #pragma unroll
        for (int mf = 0; mf < 4; ++mf) {
            a[mf][0] = *(const short8*)(base + (aRow + mf * 16) * 64 + xo0);
            a[mf][1] = *(const short8*)(base + (aRow + mf * 16) * 64 + xo1);
        }
        #pragma unroll
        for (int nf = 0; nf < 4; ++nf) {
            bfr[nf][0] = *(const short8*)(base + 16384 + (bRow + nf * 16) * 64 + xo0);
            bfr[nf][1] = *(const short8*)(base + 16384 + (bRow + nf * 16) * 64 + xo1);
        }
        __builtin_amdgcn_s_setprio(1);
        #pragma unroll
        for (int mf = 0; mf < 4; ++mf)
            #pragma unroll
            for (int nf = 0; nf < 2; ++nf)
                #pragma unroll
                for (int kk = 0; kk < 2; ++kk)
                    acc[mf][nf] = __builtin_amdgcn_mfma_f32_16x16x32_bf16(
                        a[mf][kk], bfr[nf][kk], acc[mf][nf], 0, 0, 0);
        __builtin_amdgcn_s_setprio(0);
        __syncthreads();

        // ---- p1: issue B-stage(t+2) into buf[cb] (B fully consumed at p0); MFMA Q(0, nh1) ----
        if (pf) { STAGE_B(ktp, cb); }
        __builtin_amdgcn_s_setprio(1);
        #pragma unroll
        for (int mf = 0; mf < 4; ++mf)
            #pragma unroll
            for (int nf = 2; nf < 4; ++nf)
                #pragma unroll
                for (int kk = 0; kk < 2; ++kk)
                    acc[mf][nf] = __builtin_amdgcn_mfma_f32_16x16x32_bf16(
                        a[mf][kk], bfr[nf][kk], acc[mf][nf], 0, 0, 0);
        __builtin_amdgcn_s_setprio(0);
        __syncthreads();

        // ---- p2: read A-mh1 (8, reuse regs); MFMA Q(1, nh0) ----
        #pragma unroll
        for (int mf = 0; mf < 4; ++mf) {
            a[mf][0] = *(const short8*)(base + (aRow + (mf + 4) * 16) * 64 + xo0);
            a[mf][1] = *(const short8*)(base + (aRow + (mf + 4) * 16) * 64 + xo1);
        }
        __builtin_amdgcn_s_setprio(1);
        #pragma unroll
        for (int mf = 0; mf < 4; ++mf)
            #pragma unroll
            for (int nf = 0; nf < 2; ++nf)
                #pragma unroll
                for (int kk = 0; kk < 2; ++kk)
                    acc[4 + mf][nf] = __builtin_amdgcn_mfma_f32_16x16x32_bf16(
                        a[mf][kk], bfr[nf][kk], acc[4 + mf][nf], 0, 0, 0);
        __builtin_amdgcn_s_setprio(0);
        __syncthreads();

        // ---- p3: issue A-stage(t+2) (A fully consumed at p2); MFMA Q(1, nh1) ----
        if (pf) { STAGE_A(ktp, cb); }
        __builtin_amdgcn_s_setprio(1);
        #pragma unroll
        for (int mf = 0; mf < 4; ++mf)
            #pragma unroll
            for (int nf = 2; nf < 4; ++nf)
                #pragma unroll
                for (int kk = 0; kk < 2; ++kk)
                    acc[4 + mf][nf] = __builtin_amdgcn_mfma_f32_16x16x32_bf16(
                        a[mf][kk], bfr[nf][kk], acc[4 + mf][nf], 0, 0, 0);
        __builtin_amdgcn_s_setprio(0);

        // ---- end-of-tile: counted wait (tile t+1 drained; t+2's 8 stay in flight) ----
        if (t + 1 < NT) {
            if (pf) asm volatile("s_waitcnt vmcnt(8)" ::: "memory");
            else    asm volatile("s_waitcnt vmcnt(0)" ::: "memory");
            __syncthreads();
        }
    }

    // ---- epilogue: C write (bf16) + fused column sum/sumsq ----
    const int row0 = bm * 256 + wrow * 128 + lhi * 4;
    const int col0 = bn * 256 + wcol * 64 + l15;
    #pragma unroll
    for (int mf = 0; mf < 8; ++mf)
        #pragma unroll
        for (int nf = 0; nf < 4; ++nf)
            #pragma unroll
            for (int r = 0; r < 4; ++r)
                C[(size_t)(row0 + mf * 16 + r) * N + col0 + nf * 16] = f2bf(acc[mf][nf][r]);

    float s[4] = {0, 0, 0, 0}, q[4] = {0, 0, 0, 0};
    #pragma unroll
    for (int mf = 0; mf < 8; ++mf)
        #pragma unroll
        for (int nf = 0; nf < 4; ++nf)
            #pragma unroll
            for (int r = 0; r < 4; ++r) {
                float v = acc[mf][nf][r];
                s[nf] += v; q[nf] += v * v;
            }
    #pragma unroll
    for (int nf = 0; nf < 4; ++nf) {
        s[nf] += __shfl_xor(s[nf], 16); s[nf] += __shfl_xor(s[nf], 32);
        q[nf] += __shfl_xor(q[nf], 16); q[nf] += __shfl_xor(q[nf], 32);
    }
    if (lane < 16) {
        #pragma unroll
        for (int nf = 0; nf < 4; ++nf) {
            atomicAdd(&sums[col0 + nf * 16], s[nf]);
            atomicAdd(&sqs[col0 + nf * 16], q[nf]);
        }
    }
    #undef STAGE_A
    #undef STAGE_B
}

// ---------------------------------------------------------------------------
// m97-structure 128x128 bf16 GEMM (for GEMM2: N=512) + fused column stats.
// ---------------------------------------------------------------------------
__global__ __launch_bounds__(256) void gemm_bf16(
    const unsigned short* __restrict__ A,
    const unsigned short* __restrict__ Bt,
    unsigned short* __restrict__ C,
    float* __restrict__ sums, float* __restrict__ sqs,
    int M, int N, int K)
{
    __shared__ unsigned short As[128 * 64];
    __shared__ unsigned short Bs[128 * 64];
    const int nbn = N >> 7;
    const int bm = blockIdx.x / nbn;
    const int bn = blockIdx.x % nbn;
    const int tid = threadIdx.x;
    const int lane = tid & 63;
    const int wave = tid >> 6;
    const int wr = (wave >> 1) << 6;
    const int wc = (wave & 1) << 6;

    const unsigned short* Ab = A + (size_t)(bm * 128 + (tid >> 3)) * K + (tid & 7) * 8;
    const unsigned short* Bb = Bt + (size_t)(bn * 128 + (tid >> 3)) * K + (tid & 7) * 8;
    unsigned short* Asl = &As[tid * 8];
    unsigned short* Bsl = &Bs[tid * 8];

    f32x4 acc[4][4];
    #pragma unroll
    for (int m = 0; m < 4; ++m)
        #pragma unroll
        for (int n = 0; n < 4; ++n) acc[m][n] = (f32x4){0.f, 0.f, 0.f, 0.f};

    const int frow = lane & 15;
    const int fk = (lane >> 4) * 8;

    for (int kt = 0; kt < K; kt += 64) {
        #pragma unroll
        for (int i = 0; i < 4; ++i) {
            __builtin_amdgcn_global_load_lds(
                (const __attribute__((address_space(1))) void*)(Ab + (size_t)(i * 32) * K + kt),
                (__attribute__((address_space(3))) void*)(Asl + i * 2048), 16, 0, 0);
            __builtin_amdgcn_global_load_lds(
                (const __attribute__((address_space(1))) void*)(Bb + (size_t)(i * 32) * K + kt),
                (__attribute__((address_space(3))) void*)(Bsl + i * 2048), 16, 0, 0);
        }
        __syncthreads();
        #pragma unroll
        for (int kk = 0; kk < 64; kk += 32) {
            short8 af[4], bfv[4];
            #pragma unroll
            for (int m = 0; m < 4; ++m)
                af[m] = *(const short8*)&As[(wr + m * 16 + frow) * 64 + kk + fk];
            #pragma unroll
            for (int n = 0; n < 4; ++n)
                bfv[n] = *(const short8*)&Bs[(wc + n * 16 + frow) * 64 + kk + fk];
            #pragma unroll
            for (int m = 0; m < 4; ++m)
                #pragma unroll
                for (int n = 0; n < 4; ++n)
                    acc[m][n] = __builtin_amdgcn_mfma_f32_16x16x32_bf16(
                        af[m], bfv[n], acc[m][n], 0, 0, 0);
        }
        __syncthreads();
    }

    const int row0 = bm * 128 + wr + (lane >> 4) * 4;
    const int col0 = bn * 128 + wc + (lane & 15);
    #pragma unroll
    for (int m = 0; m < 4; ++m)
        #pragma unroll
        for (int n = 0; n < 4; ++n)
            #pragma unroll
            for (int r = 0; r < 4; ++r)
                C[(size_t)(row0 + m * 16 + r) * N + col0 + n * 16] = f2bf(acc[m][n][r]);

    float s[4] = {0, 0, 0, 0}, q[4] = {0, 0, 0, 0};
    #pragma unroll
    for (int m = 0; m < 4; ++m)
        #pragma unroll
        for (int n = 0; n < 4; ++n)
            #pragma unroll
            for (int r = 0; r < 4; ++r) {
                float v = acc[m][n][r];
                s[n] += v; q[n] += v * v;
            }
    #pragma unroll
    for (int n = 0; n < 4; ++n) {
        s[n] += __shfl_xor(s[n], 16); s[n] += __shfl_xor(s[n], 32);
        q[n] += __shfl_xor(q[n], 16); q[n] += __shfl_xor(q[n], 32);
    }
    if (lane < 16) {
        #pragma unroll
        for (int n = 0; n < 4; ++n) {
            atomicAdd(&sums[col0 + n * 16], s[n]);
            atomicAdd(&sqs[col0 + n * 16], q[n]);
        }
    }
}

// scale/shift per column: a = g*rsqrt(var+eps), b = be - mu*a   (b1/b2 cancel)
__global__ void bn_finalize(const float* __restrict__ sums, const float* __restrict__ sqs,
                            const float* __restrict__ g, const float* __restrict__ be,
                            int cols, float invB,
                            float* __restrict__ a, float* __restrict__ b)
{
    int c = blockIdx.x * 256 + threadIdx.x;
    if (c >= cols) return;
    float mu = sums[c] * invB;
    float var = sqs[c] * invB - mu * mu;
    float sc = g[c] * rsqrtf(var + 1e-5f);
    a[c] = sc;
    b[c] = be[c] - mu * sc;
}

// h = bf16(relu(a[c]*z + b[c])), 8 elems / thread
__global__ __launch_bounds__(256) void bn_relu_cast(
    const unsigned short* __restrict__ z, const float* __restrict__ a,
    const float* __restrict__ b, unsigned short* __restrict__ h,
    int cols, size_t n8)
{
    size_t id = (size_t)blockIdx.x * blockDim.x + threadIdx.x;
    if (id >= n8) return;
    size_t base = id * 8;
    int c0 = (int)(base % cols);
    u16x8 u = *(const u16x8*)&z[base];
    u16x8 o;
    #pragma unroll
    for (int j = 0; j < 8; ++j) {
        float x = a[c0 + j] * bf2f(u[j]) + b[c0 + j];
        o[j] = f2bf(fmaxf(x, 0.f));
    }
    *(u16x8*)&h[base] = o;
}

// ---------------------------------------------------------------------------
// Final: BN2 + ReLU + dot(W3) + b3 + fm -> sigmoid -> [1-p, p]
// ---------------------------------------------------------------------------
__global__ __launch_bounds__(256) void final_k(
    const unsigned short* __restrict__ z2, const float* __restrict__ a2,
    const float* __restrict__ b2, const float* __restrict__ W3,
    const float* __restrict__ b3, const float* __restrict__ fm,
    float* __restrict__ out)
{
    int row = blockIdx.x * 4 + threadIdx.y;
    int lane = threadIdx.x;
    int c = lane * 8;
    u16x8 u = *(const u16x8*)&z2[(size_t)row * 512 + c];
    float dot = 0.f;
    #pragma unroll
    for (int j = 0; j < 8; ++j) {
        float x = a2[c + j] * bf2f(u[j]) + b2[c + j];
        dot += fmaxf(x, 0.f) * W3[c + j];
    }
    #pragma unroll
    for (int off = 32; off; off >>= 1) dot += __shfl_xor(dot, off);
    if (lane == 0) {
        float logit = fm[row] + dot + b3[0];
        float p = 1.f / (1.f + expf(-logit));
        out[row * 2 + 0] = 1.f - p;
        out[row * 2 + 1] = p;
    }
}

// ---------------------------------------------------------------------------
extern "C" void kernel_launch(void* const* d_in, const int* in_sizes, int n_in,
                              void* d_out, int out_size, void* d_ws, size_t ws_size,
                              hipStream_t stream)
{
    const int*   cat  = (const int*)d_in[0];
    const float* cont = (const float*)d_in[1];
    const float* bias = (const float*)d_in[2];
    const float* t1c  = (const float*)d_in[3];
    const float* t2c  = (const float*)d_in[4];
    const float* t1x  = (const float*)d_in[5];
    const float* t2x  = (const float*)d_in[6];
    const float* W1   = (const float*)d_in[7];
    // d_in[8] = b1: cancels under training-mode BN
    const float* g1   = (const float*)d_in[9];
    const float* be1  = (const float*)d_in[10];
    const float* W2   = (const float*)d_in[11];
    // d_in[12] = b2: cancels
    const float* g2   = (const float*)d_in[13];
    const float* be2  = (const float*)d_in[14];
    const float* W3   = (const float*)d_in[15];
    const float* b3   = (const float*)d_in[16];
    float* out = (float*)d_out;

    const int B = 16384, IN_DIM = 2496, KP = 2560, H1 = 1024, H2 = 512;

    uint8_t* p = (uint8_t*)d_ws;
    auto carve = [&](size_t bytes) {
        uint8_t* r = p;
        p += (bytes + 255) & ~(size_t)255;
        return r;
    };
    unsigned short* deep = (unsigned short*)carve((size_t)B * KP * 2);   // 83.9 MB
    unsigned short* w1t  = (unsigned short*)carve((size_t)H1 * KP * 2);
    unsigned short* w2t  = (unsigned short*)carve((size_t)H2 * H1 * 2);
    unsigned short* z1   = (unsigned short*)carve((size_t)B * H1 * 2);
    unsigned short* h1   = (unsigned short*)carve((size_t)B * H1 * 2);
    unsigned short* z2   = (unsigned short*)carve((size_t)B * H2 * 2);
    float* fm    = (float*)carve((size_t)B * 4);
    float* stats = (float*)carve((size_t)(H1 * 2 + H2 * 2) * 4);
    float* sums1 = stats, *sqs1 = stats + H1, *sums2 = stats + 2 * H1, *sqs2 = stats + 2 * H1 + H2;
    float* a1  = (float*)carve(H1 * 4);
    float* b1c = (float*)carve(H1 * 4);
    float* a2  = (float*)carve(H2 * 4);
    float* b2c = (float*)carve(H2 * 4);

    hipMemsetAsync(stats, 0, (size_t)(H1 * 2 + H2 * 2) * 4, stream);

    dim3 tb(32, 8);
    transpose_cast<<<dim3(H1 / 32, KP / 32), tb, 0, stream>>>(W1, w1t, IN_DIM, H1, KP);
    transpose_cast<<<dim3(H2 / 32, H1 / 32), tb, 0, stream>>>(W2, w2t, H1, H2, H1);

    embed_fm<<<B / 4, dim3(64, 4), 0, stream>>>(cat, cont, bias, t1c, t2c, t1x, t2x, deep, fm);

    // GEMM1: 256^2 8-wave pipelined tile, fused BN1 stats
    gemm256<<<(B / 256) * (H1 / 256), 512, 0, stream>>>(deep, w1t, z1, sums1, sqs1, B, H1, KP);

    bn_finalize<<<(H1 + 255) / 256, 256, 0, stream>>>(sums1, sqs1, g1, be1, H1, 1.f / B, a1, b1c);
    bn_relu_cast<<<(int)(((size_t)B * H1 / 8 + 255) / 256), 256, 0, stream>>>(
        z1, a1, b1c, h1, H1, (size_t)B * H1 / 8);

    // GEMM2: 128^2 tile, fused BN2 stats
    gemm_bf16<<<(B / 128) * (H2 / 128), 256, 0, stream>>>(h1, w2t, z2, sums2, sqs2, B, H2, H1);

    bn_finalize<<<(H2 + 255) / 256, 256, 0, stream>>>(sums2, sqs2, g2, be2, H2, 1.f / B, a2, b2c);

    final_k<<<B / 4, dim3(64, 4), 0, stream>>>(z2, a2, b2c, W3, b3, fm, out);
}

// Round 3
// 179.229 us; speedup vs baseline: 2.0434x; 1.5258x over previous
//
#include <hip/hip_runtime.h>
#include <stdint.h>

typedef __attribute__((ext_vector_type(8))) short short8;
typedef __attribute__((ext_vector_type(8))) unsigned short u16x8;
typedef __attribute__((ext_vector_type(4))) float f32x4;

#define DEV __device__ __forceinline__

DEV float bf2f(unsigned short v) {
    union { unsigned int u; float f; } c;
    c.u = ((unsigned int)v) << 16;
    return c.f;
}
DEV unsigned short f2bf(float f) {
    union { float f; unsigned int u; } c;
    c.f = f;
    unsigned int x = c.u;
    x += 0x7fffu + ((x >> 16) & 1u);   // round-to-nearest-even
    return (unsigned short)(x >> 16);
}

// ---------------------------------------------------------------------------
// K1: embedding gather + FM first/second order + write deep (bf16, K=2496)
// block (64,4): lane = d (0..63), 4 batch rows per block.
// ---------------------------------------------------------------------------
__global__ __launch_bounds__(256) void embed_fm(
    const int* __restrict__ cat, const float* __restrict__ cont,
    const float* __restrict__ bias,
    const float* __restrict__ t1c, const float* __restrict__ t2c,
    const float* __restrict__ t1x, const float* __restrict__ t2x,
    unsigned short* __restrict__ deep, float* __restrict__ fm)
{
    __shared__ unsigned short rowbuf[4][2496];   // 19.5 KiB
    const int ty = threadIdx.y;
    const int row = blockIdx.x * 4 + ty;
    const int d = threadIdx.x;
    const int* crow = cat + row * 26;
    const float* xrow = cont + row * 13;

    float s = 0.f, ss = 0.f;
    #pragma unroll
    for (int f = 0; f < 26; ++f) {
        int idx = crow[f];                                  // wave-uniform load
        float e = t2c[((size_t)f * 100000 + idx) * 64 + d]; // coalesced 256B row
        s += e; ss += e * e;
        rowbuf[ty][f * 64 + d] = f2bf(e);
    }
    #pragma unroll
    for (int f = 0; f < 13; ++f) {
        float x = xrow[f];
        float e = t2x[f * 64 + d] * x;
        s += e; ss += e * e;
        rowbuf[ty][(26 + f) * 64 + d] = f2bf(e);
    }

    float val = 0.5f * (s * s - ss);
    if (d < 26) val += t1c[(size_t)d * 100000 + crow[d]];
    if (d < 13) val += t1x[d] * xrow[d];
    #pragma unroll
    for (int off = 32; off; off >>= 1) val += __shfl_xor(val, off);
    if (d == 0) fm[row] = bias[0] + val;

    __syncthreads();
    // cooperative coalesced store: 4 rows x 2496 = 9984 elems = 1248 x 8-elem chunks
    const int tid = ty * 64 + d;
    const unsigned short* src = &rowbuf[0][0];
    unsigned short* dst = deep + (size_t)(blockIdx.x * 4) * 2496;
    #pragma unroll
    for (int it = 0; it < 5; ++it) {
        int off = it * 2048 + tid * 8;
        if (off < 9984)
            *(u16x8*)(dst + off) = *(const u16x8*)(src + off);
    }
}

// ---------------------------------------------------------------------------
// Merged transpose + fp32->bf16 cast for W1 (2496x1024 -> 1024x2496) and
// W2 (1024x512 -> 512x1024). block (32,8); one flattened grid.
// ---------------------------------------------------------------------------
__global__ __launch_bounds__(256) void transpose_both(
    const float* __restrict__ W1, unsigned short* __restrict__ w1t,
    const float* __restrict__ W2, unsigned short* __restrict__ w2t)
{
    __shared__ float tile[32][33];
    int b = blockIdx.x;
    const float* in; unsigned short* out; int R, C, bx, by;
    if (b < 2496) { in = W1; out = w1t; R = 2496; C = 1024; bx = b % 32; by = b / 32; }
    else { b -= 2496; in = W2; out = w2t; R = 1024; C = 512; bx = b % 16; by = b / 16; }
    int c0 = bx * 32, r0 = by * 32;
    int tx = threadIdx.x, ty = threadIdx.y;
    #pragma unroll
    for (int i = 0; i < 4; ++i)
        tile[ty + i * 8][tx] = in[(size_t)(r0 + ty + i * 8) * C + c0 + tx];
    __syncthreads();
    #pragma unroll
    for (int i = 0; i < 4; ++i)
        out[(size_t)(c0 + ty + i * 8) * R + r0 + tx] = f2bf(tile[tx][ty + i * 8]);
}

// ---------------------------------------------------------------------------
// GEMM1: 256x256-tile 8-wave bf16 GEMM, TRUE counted-vmcnt pipeline (raw
// s_barrier, no compiler vmcnt(0) drain), LDS XOR swizzle, setprio, fused
// per-column sum/sumsq epilogue.  C[M,N] = A[M,K]*Bt[N,K]^T, K%64==0, NT>=3.
//
// Per tile t (buf cb = t&1), 3 barriers:
//   pA: ds_read A-mh0(8) + B-all(8); 32 MFMA Q(0,*)   [consumes ALL B regs]
//   bar1  (every wave's B ds_reads completed -- lgkm wait precedes its MFMAs)
//   pB: issue STAGE_B(t+2)->buf[cb].B (safe: B consumed); ds_read A-mh1(8);
//       32 MFMA Q(1,*)                                [consumes ALL A regs]
//   bar2  (A consumed)
//   pC: issue STAGE_A(t+2)->buf[cb].A; s_waitcnt vmcnt(8) -- drains tile
//       t+1's 8 loads, leaves t+2's 8 in flight; bar3.
// ---------------------------------------------------------------------------
__global__ __launch_bounds__(512, 2) void gemm256(
    const unsigned short* __restrict__ A,
    const unsigned short* __restrict__ Bt,
    unsigned short* __restrict__ C,
    float* __restrict__ sums, float* __restrict__ sqs,
    int M, int N, int K)
{
    __shared__ unsigned short lds[2][32768];   // [buf][A:0..16384 | B:16384..32768]
    const int tid = threadIdx.x;
    const int lane = tid & 63, wid = tid >> 6;
    const int wrow = wid >> 2, wcol = wid & 3;
    const int nbn = N >> 8;
    const int bm = blockIdx.x / nbn, bn = blockIdx.x % nbn;
    const int NT = K >> 6;

    // staging: pre-swizzled global source, linear LDS dest (guide rule #21)
    const int srow = tid >> 3;
    const int skc  = (tid & 7) ^ (srow & 7);
    const unsigned short* Asrc = A + (size_t)(bm * 256 + srow) * K + skc * 8;
    const unsigned short* Bsrc = Bt + (size_t)(bn * 256 + srow) * K + skc * 8;

    #define STAGE_A(kt, b)                                                        \
        _Pragma("unroll")                                                         \
        for (int i_ = 0; i_ < 4; ++i_)                                            \
            __builtin_amdgcn_global_load_lds(                                     \
                (const __attribute__((address_space(1))) void*)(Asrc + (size_t)(i_ * 64) * K + (kt)), \
                (__attribute__((address_space(3))) void*)(&lds[b][tid * 8 + i_ * 4096]), 16, 0, 0);
    #define STAGE_B(kt, b)                                                        \
        _Pragma("unroll")                                                         \
        for (int i_ = 0; i_ < 4; ++i_)                                            \
            __builtin_amdgcn_global_load_lds(                                     \
                (const __attribute__((address_space(1))) void*)(Bsrc + (size_t)(i_ * 64) * K + (kt)), \
                (__attribute__((address_space(3))) void*)(&lds[b][16384 + tid * 8 + i_ * 4096]), 16, 0, 0);

    // fragment read offsets (swizzled; 2 lanes/bank-quad -> conflict-free)
    const int l15 = lane & 15, l7 = lane & 7, lhi = lane >> 4;
    const int xo0 = 8 * (lhi ^ l7);
    const int xo1 = 8 * ((lhi + 4) ^ l7);
    const int aRow = wrow * 128 + l15;
    const int bRow = wcol * 64 + l15;

    f32x4 acc[8][4];
    #pragma unroll
    for (int m = 0; m < 8; ++m)
        #pragma unroll
        for (int n = 0; n < 4; ++n) acc[m][n] = (f32x4){0.f, 0.f, 0.f, 0.f};

    STAGE_A(0, 0); STAGE_B(0, 0);
    STAGE_A(64, 1); STAGE_B(64, 1);
    asm volatile("s_waitcnt vmcnt(8)" ::: "memory");
    __builtin_amdgcn_s_barrier();

    for (int t = 0; t < NT; ++t) {
        const int cb = t & 1;
        const unsigned short* base = &lds[cb][0];
        const int ktp = (t + 2) << 6;
        const bool pf = (t + 2) < NT;

        short8 a[4][2], bfr[4][2];
        // ---- pA: read A-mh0 + all B; MFMA Q(0,*) x32 ----
        #pragma unroll
        for (int mf = 0; mf < 4; ++mf) {
            a[mf][0] = *(const short8*)(base + (aRow + mf * 16) * 64 + xo0);
            a[mf][1] = *(const short8*)(base + (aRow + mf * 16) * 64 + xo1);
        }
        #pragma unroll
        for (int nf = 0; nf < 4; ++nf) {
            bfr[nf][0] = *(const short8*)(base + 16384 + (bRow + nf * 16) * 64 + xo0);
            bfr[nf][1] = *(const short8*)(base + 16384 + (bRow + nf * 16) * 64 + xo1);
        }
        __builtin_amdgcn_s_setprio(1);
        #pragma unroll
        for (int mf = 0; mf < 4; ++mf)
            #pragma unroll
            for (int nf = 0; nf < 4; ++nf)
                #pragma unroll
                for (int kk = 0; kk < 2; ++kk)
                    acc[mf][nf] = __builtin_amdgcn_mfma_f32_16x16x32_bf16(
                        a[mf][kk], bfr[nf][kk], acc[mf][nf], 0, 0, 0);
        __builtin_amdgcn_s_setprio(0);
        __builtin_amdgcn_s_barrier();   // bar1: all waves consumed B region

        // ---- pB: stage B(t+2); read A-mh1; MFMA Q(1,*) x32 ----
        if (pf) { STAGE_B(ktp, cb); }
        #pragma unroll
        for (int mf = 0; mf < 4; ++mf) {
            a[mf][0] = *(const short8*)(base + (aRow + (mf + 4) * 16) * 64 + xo0);
            a[mf][1] = *(const short8*)(base + (aRow + (mf + 4) * 16) * 64 + xo1);
        }
        __builtin_amdgcn_s_setprio(1);
        #pragma unroll
        for (int mf = 0; mf < 4; ++mf)
            #pragma unroll
            for (int nf = 0; nf < 4; ++nf)
                #pragma unroll
                for (int kk = 0; kk < 2; ++kk)
                    acc[4 + mf][nf] = __builtin_amdgcn_mfma_f32_16x16x32_bf16(
                        a[mf][kk], bfr[nf][kk], acc[4 + mf][nf], 0, 0, 0);
        __builtin_amdgcn_s_setprio(0);
        __builtin_amdgcn_s_barrier();   // bar2: all waves consumed A region

        // ---- pC: stage A(t+2); counted wait for tile t+1; barrier ----
        if (t + 1 < NT) {
            if (pf) {
                STAGE_A(ktp, cb);
                asm volatile("s_waitcnt vmcnt(8)" ::: "memory");
            } else {
                asm volatile("s_waitcnt vmcnt(0)" ::: "memory");
            }
            __builtin_amdgcn_s_barrier();   // bar3: tile t+1 data visible to all
        }
    }

    // ---- epilogue: C write (bf16) + fused column sum/sumsq ----
    const int row0 = bm * 256 + wrow * 128 + lhi * 4;
    const int col0 = bn * 256 + wcol * 64 + l15;
    #pragma unroll
    for (int mf = 0; mf < 8; ++mf)
        #pragma unroll
        for (int nf = 0; nf < 4; ++nf)
            #pragma unroll
            for (int r = 0; r < 4; ++r)
                C[(size_t)(row0 + mf * 16 + r) * N + col0 + nf * 16] = f2bf(acc[mf][nf][r]);

    float s[4] = {0, 0, 0, 0}, q[4] = {0, 0, 0, 0};
    #pragma unroll
    for (int mf = 0; mf < 8; ++mf)
        #pragma unroll
        for (int nf = 0; nf < 4; ++nf)
            #pragma unroll
            for (int r = 0; r < 4; ++r) {
                float v = acc[mf][nf][r];
                s[nf] += v; q[nf] += v * v;
            }
    #pragma unroll
    for (int nf = 0; nf < 4; ++nf) {
        s[nf] += __shfl_xor(s[nf], 16); s[nf] += __shfl_xor(s[nf], 32);
        q[nf] += __shfl_xor(q[nf], 16); q[nf] += __shfl_xor(q[nf], 32);
    }
    if (lane < 16) {
        #pragma unroll
        for (int nf = 0; nf < 4; ++nf) {
            atomicAdd(&sums[col0 + nf * 16], s[nf]);
            atomicAdd(&sqs[col0 + nf * 16], q[nf]);
        }
    }
    #undef STAGE_A
    #undef STAGE_B
}

// ---------------------------------------------------------------------------
// GEMM2 fused: A = relu(BN1(z1)) computed in-flight during reg-staged A
// (BN1 coefficients derived from raw sums/sqs once per block into LDS);
// B via global_load_lds; fused column stats for BN2.  128x128 tile, m97 loop.
// ---------------------------------------------------------------------------
__global__ __launch_bounds__(256) void gemm2_fused(
    const unsigned short* __restrict__ z1,
    const unsigned short* __restrict__ Bt,
    unsigned short* __restrict__ C,
    const float* __restrict__ sums1, const float* __restrict__ sqs1,
    const float* __restrict__ g1, const float* __restrict__ be1,
    float* __restrict__ sums2, float* __restrict__ sqs2,
    int M, int N, int K, float invB)
{
    __shared__ unsigned short As[128 * 64];
    __shared__ unsigned short Bs[128 * 64];
    __shared__ float a1s[1024], b1s[1024];
    const int nbn = N >> 7;
    const int bm = blockIdx.x / nbn;
    const int bn = blockIdx.x % nbn;
    const int tid = threadIdx.x;
    const int lane = tid & 63;
    const int wave = tid >> 6;
    const int wr = (wave >> 1) << 6;
    const int wc = (wave & 1) << 6;

    // BN1 coefficients (folds bn_finalize): once per block
    for (int c = tid; c < K; c += 256) {
        float mu = sums1[c] * invB;
        float var = sqs1[c] * invB - mu * mu;
        float sc = g1[c] * rsqrtf(var + 1e-5f);
        a1s[c] = sc;
        b1s[c] = be1[c] - mu * sc;
    }
    __syncthreads();

    const int arow = bm * 128 + (tid >> 3);
    const int acol = (tid & 7) * 8;
    const unsigned short* Bb = Bt + (size_t)(bn * 128 + (tid >> 3)) * K + acol;
    unsigned short* Bsl = &Bs[tid * 8];

    f32x4 acc[4][4];
    #pragma unroll
    for (int m = 0; m < 4; ++m)
        #pragma unroll
        for (int n = 0; n < 4; ++n) acc[m][n] = (f32x4){0.f, 0.f, 0.f, 0.f};

    const int frow = lane & 15;
    const int fk = (lane >> 4) * 8;

    for (int kt = 0; kt < K; kt += 64) {
        // B staging: async global->LDS
        #pragma unroll
        for (int i = 0; i < 4; ++i)
            __builtin_amdgcn_global_load_lds(
                (const __attribute__((address_space(1))) void*)(Bb + (size_t)(i * 32) * K + kt),
                (__attribute__((address_space(3))) void*)(Bsl + i * 2048), 16, 0, 0);
        // A staging: reg-staged z1 with BN1+ReLU applied in flight
        u16x8 va[4];
        #pragma unroll
        for (int i = 0; i < 4; ++i)
            va[i] = *(const u16x8*)&z1[(size_t)(arow + i * 32) * K + kt + acol];
        const int c0 = kt + acol;
        float4 av0 = *(const float4*)&a1s[c0];
        float4 av1 = *(const float4*)&a1s[c0 + 4];
        float4 bv0 = *(const float4*)&b1s[c0];
        float4 bv1 = *(const float4*)&b1s[c0 + 4];
        float av[8] = {av0.x, av0.y, av0.z, av0.w, av1.x, av1.y, av1.z, av1.w};
        float bv[8] = {bv0.x, bv0.y, bv0.z, bv0.w, bv1.x, bv1.y, bv1.z, bv1.w};
        #pragma unroll
        for (int i = 0; i < 4; ++i) {
            short8 w;
            #pragma unroll
            for (int j = 0; j < 8; ++j)
                w[j] = (short)f2bf(fmaxf(av[j] * bf2f(va[i][j]) + bv[j], 0.f));
            *(short8*)&As[tid * 8 + i * 2048] = w;
        }
        __syncthreads();
        #pragma unroll
        for (int kk = 0; kk < 64; kk += 32) {
            short8 af[4], bfv[4];
            #pragma unroll
            for (int m = 0; m < 4; ++m)
                af[m] = *(const short8*)&As[(wr + m * 16 + frow) * 64 + kk + fk];
            #pragma unroll
            for (int n = 0; n < 4; ++n)
                bfv[n] = *(const short8*)&Bs[(wc + n * 16 + frow) * 64 + kk + fk];
            #pragma unroll
            for (int m = 0; m < 4; ++m)
                #pragma unroll
                for (int n = 0; n < 4; ++n)
                    acc[m][n] = __builtin_amdgcn_mfma_f32_16x16x32_bf16(
                        af[m], bfv[n], acc[m][n], 0, 0, 0);
        }
        __syncthreads();
    }

    const int row0 = bm * 128 + wr + (lane >> 4) * 4;
    const int col0 = bn * 128 + wc + (lane & 15);
    #pragma unroll
    for (int m = 0; m < 4; ++m)
        #pragma unroll
        for (int n = 0; n < 4; ++n)
            #pragma unroll
            for (int r = 0; r < 4; ++r)
                C[(size_t)(row0 + m * 16 + r) * N + col0 + n * 16] = f2bf(acc[m][n][r]);

    float s[4] = {0, 0, 0, 0}, q[4] = {0, 0, 0, 0};
    #pragma unroll
    for (int m = 0; m < 4; ++m)
        #pragma unroll
        for (int n = 0; n < 4; ++n)
            #pragma unroll
            for (int r = 0; r < 4; ++r) {
                float v = acc[m][n][r];
                s[n] += v; q[n] += v * v;
            }
    #pragma unroll
    for (int n = 0; n < 4; ++n) {
        s[n] += __shfl_xor(s[n], 16); s[n] += __shfl_xor(s[n], 32);
        q[n] += __shfl_xor(q[n], 16); q[n] += __shfl_xor(q[n], 32);
    }
    if (lane < 16) {
        #pragma unroll
        for (int n = 0; n < 4; ++n) {
            atomicAdd(&sums2[col0 + n * 16], s[n]);
            atomicAdd(&sqs2[col0 + n * 16], q[n]);
        }
    }
}

// ---------------------------------------------------------------------------
// Final: BN2 (coeffs from raw stats, folded) + ReLU + dot(W3) + b3 + fm
// -> sigmoid -> [1-p, p].  block (64,4): one wave per row.
// ---------------------------------------------------------------------------
__global__ __launch_bounds__(256) void final_k(
    const unsigned short* __restrict__ z2,
    const float* __restrict__ sums2, const float* __restrict__ sqs2,
    const float* __restrict__ g2, const float* __restrict__ be2,
    const float* __restrict__ W3, const float* __restrict__ b3,
    const float* __restrict__ fm, float* __restrict__ out, float invB)
{
    int row = blockIdx.x * 4 + threadIdx.y;
    int lane = threadIdx.x;
    int c = lane * 8;
    u16x8 u = *(const u16x8*)&z2[(size_t)row * 512 + c];
    float dot = 0.f;
    #pragma unroll
    for (int j = 0; j < 8; ++j) {
        float mu = sums2[c + j] * invB;
        float var = sqs2[c + j] * invB - mu * mu;
        float a = g2[c + j] * rsqrtf(var + 1e-5f);
        float b = be2[c + j] - mu * a;
        float x = a * bf2f(u[j]) + b;
        dot += fmaxf(x, 0.f) * W3[c + j];
    }
    #pragma unroll
    for (int off = 32; off; off >>= 1) dot += __shfl_xor(dot, off);
    if (lane == 0) {
        float logit = fm[row] + dot + b3[0];
        float p = 1.f / (1.f + expf(-logit));
        out[row * 2 + 0] = 1.f - p;
        out[row * 2 + 1] = p;
    }
}

// ---------------------------------------------------------------------------
extern "C" void kernel_launch(void* const* d_in, const int* in_sizes, int n_in,
                              void* d_out, int out_size, void* d_ws, size_t ws_size,
                              hipStream_t stream)
{
    const int*   cat  = (const int*)d_in[0];
    const float* cont = (const float*)d_in[1];
    const float* bias = (const float*)d_in[2];
    const float* t1c  = (const float*)d_in[3];
    const float* t2c  = (const float*)d_in[4];
    const float* t1x  = (const float*)d_in[5];
    const float* t2x  = (const float*)d_in[6];
    const float* W1   = (const float*)d_in[7];
    // d_in[8] = b1: cancels under training-mode BN
    const float* g1   = (const float*)d_in[9];
    const float* be1  = (const float*)d_in[10];
    const float* W2   = (const float*)d_in[11];
    // d_in[12] = b2: cancels
    const float* g2   = (const float*)d_in[13];
    const float* be2  = (const float*)d_in[14];
    const float* W3   = (const float*)d_in[15];
    const float* b3   = (const float*)d_in[16];
    float* out = (float*)d_out;

    const int B = 16384, K1 = 2496, H1 = 1024, H2 = 512;

    uint8_t* p = (uint8_t*)d_ws;
    auto carve = [&](size_t bytes) {
        uint8_t* r = p;
        p += (bytes + 255) & ~(size_t)255;
        return r;
    };
    unsigned short* deep = (unsigned short*)carve((size_t)B * K1 * 2);   // 81.8 MB
    unsigned short* w1t  = (unsigned short*)carve((size_t)H1 * K1 * 2);
    unsigned short* w2t  = (unsigned short*)carve((size_t)H2 * H1 * 2);
    unsigned short* z1   = (unsigned short*)carve((size_t)B * H1 * 2);
    unsigned short* z2   = (unsigned short*)carve((size_t)B * H2 * 2);
    float* fm    = (float*)carve((size_t)B * 4);
    float* stats = (float*)carve((size_t)(H1 * 2 + H2 * 2) * 4);
    float* sums1 = stats, *sqs1 = stats + H1, *sums2 = stats + 2 * H1, *sqs2 = stats + 2 * H1 + H2;

    hipMemsetAsync(stats, 0, (size_t)(H1 * 2 + H2 * 2) * 4, stream);

    // W1 + W2 transpose/cast in one launch: 2496 + 512 = 3008 blocks
    transpose_both<<<3008, dim3(32, 8), 0, stream>>>(W1, w1t, W2, w2t);

    embed_fm<<<B / 4, dim3(64, 4), 0, stream>>>(cat, cont, bias, t1c, t2c, t1x, t2x, deep, fm);

    // GEMM1: 256^2 tile, true counted-vmcnt pipeline, fused BN1 stats
    gemm256<<<(B / 256) * (H1 / 256), 512, 0, stream>>>(deep, w1t, z1, sums1, sqs1, B, H1, K1);

    // GEMM2: BN1-apply+ReLU fused into A staging, fused BN2 stats
    gemm2_fused<<<(B / 128) * (H2 / 128), 256, 0, stream>>>(
        z1, w2t, z2, sums1, sqs1, g1, be1, sums2, sqs2, B, H2, H1, 1.f / B);

    final_k<<<B / 4, dim3(64, 4), 0, stream>>>(z2, sums2, sqs2, g2, be2, W3, b3, fm, out, 1.f / B);
}

// Round 4
// 178.940 us; speedup vs baseline: 2.0467x; 1.0016x over previous
//
#include <hip/hip_runtime.h>
#include <stdint.h>

typedef __attribute__((ext_vector_type(8))) short short8;
typedef __attribute__((ext_vector_type(8))) unsigned short u16x8;
typedef __attribute__((ext_vector_type(4))) float f32x4;

#define DEV __device__ __forceinline__

DEV float bf2f(unsigned short v) {
    union { unsigned int u; float f; } c;
    c.u = ((unsigned int)v) << 16;
    return c.f;
}
DEV unsigned short f2bf(float f) {
    union { float f; unsigned int u; } c;
    c.f = f;
    unsigned int x = c.u;
    x += 0x7fffu + ((x >> 16) & 1u);   // round-to-nearest-even
    return (unsigned short)(x >> 16);
}

// ---------------------------------------------------------------------------
// K1: embedding gather + FM first/second order + write deep (bf16, K=2496)
// block (64,4): lane = d (0..63), 4 batch rows per block.
// ---------------------------------------------------------------------------
__global__ __launch_bounds__(256) void embed_fm(
    const int* __restrict__ cat, const float* __restrict__ cont,
    const float* __restrict__ bias,
    const float* __restrict__ t1c, const float* __restrict__ t2c,
    const float* __restrict__ t1x, const float* __restrict__ t2x,
    unsigned short* __restrict__ deep, float* __restrict__ fm)
{
    __shared__ unsigned short rowbuf[4][2496];   // 19.5 KiB
    const int ty = threadIdx.y;
    const int row = blockIdx.x * 4 + ty;
    const int d = threadIdx.x;
    const int* crow = cat + row * 26;
    const float* xrow = cont + row * 13;

    float s = 0.f, ss = 0.f;
    #pragma unroll
    for (int f = 0; f < 26; ++f) {
        int idx = crow[f];                                  // wave-uniform load
        float e = t2c[((size_t)f * 100000 + idx) * 64 + d]; // coalesced 256B row
        s += e; ss += e * e;
        rowbuf[ty][f * 64 + d] = f2bf(e);
    }
    #pragma unroll
    for (int f = 0; f < 13; ++f) {
        float x = xrow[f];
        float e = t2x[f * 64 + d] * x;
        s += e; ss += e * e;
        rowbuf[ty][(26 + f) * 64 + d] = f2bf(e);
    }

    float val = 0.5f * (s * s - ss);
    if (d < 26) val += t1c[(size_t)d * 100000 + crow[d]];
    if (d < 13) val += t1x[d] * xrow[d];
    #pragma unroll
    for (int off = 32; off; off >>= 1) val += __shfl_xor(val, off);
    if (d == 0) fm[row] = bias[0] + val;

    __syncthreads();
    // cooperative coalesced store: 4 rows x 2496 = 9984 elems = 1248 x 8-elem chunks
    const int tid = ty * 64 + d;
    const unsigned short* src = &rowbuf[0][0];
    unsigned short* dst = deep + (size_t)(blockIdx.x * 4) * 2496;
    #pragma unroll
    for (int it = 0; it < 5; ++it) {
        int off = it * 2048 + tid * 8;
        if (off < 9984)
            *(u16x8*)(dst + off) = *(const u16x8*)(src + off);
    }
}

// ---------------------------------------------------------------------------
// Merged transpose + fp32->bf16 cast for W1 (2496x1024 -> 1024x2496) and
// W2 (1024x512 -> 512x1024). block (32,8); one flattened grid.
// ---------------------------------------------------------------------------
__global__ __launch_bounds__(256) void transpose_both(
    const float* __restrict__ W1, unsigned short* __restrict__ w1t,
    const float* __restrict__ W2, unsigned short* __restrict__ w2t)
{
    __shared__ float tile[32][33];
    int b = blockIdx.x;
    const float* in; unsigned short* out; int R, C, bx, by;
    if (b < 2496) { in = W1; out = w1t; R = 2496; C = 1024; bx = b % 32; by = b / 32; }
    else { b -= 2496; in = W2; out = w2t; R = 1024; C = 512; bx = b % 16; by = b / 16; }
    int c0 = bx * 32, r0 = by * 32;
    int tx = threadIdx.x, ty = threadIdx.y;
    #pragma unroll
    for (int i = 0; i < 4; ++i)
        tile[ty + i * 8][tx] = in[(size_t)(r0 + ty + i * 8) * C + c0 + tx];
    __syncthreads();
    #pragma unroll
    for (int i = 0; i < 4; ++i)
        out[(size_t)(c0 + ty + i * 8) * R + r0 + tx] = f2bf(tile[tx][ty + i * 8]);
}

// ---------------------------------------------------------------------------
// GEMM1: 256x256-tile 8-wave bf16 GEMM, TRUE counted-vmcnt pipeline (raw
// s_barrier, no compiler vmcnt(0) drain), LDS XOR swizzle, setprio, fused
// per-column sum/sumsq epilogue.  C[M,N] = A[M,K]*Bt[N,K]^T, K%64==0, NT>=3.
//
// Per tile t (buf cb = t&1), 3 barriers:
//   pA: ds_read A-mh0(8) + B-all(8); 32 MFMA Q(0,*)   [consumes ALL B regs]
//   bar1  (every wave's B ds_reads completed -- lgkm wait precedes its MFMAs)
//   pB: issue STAGE_B(t+2)->buf[cb].B (safe: B consumed); ds_read A-mh1(8);
//       32 MFMA Q(1,*)                                [consumes ALL A regs]
//   bar2  (A consumed)
//   pC: issue STAGE_A(t+2)->buf[cb].A; s_waitcnt vmcnt(8) -- drains tile
//       t+1's 8 loads, leaves t+2's 8 in flight; bar3.
// ---------------------------------------------------------------------------
__global__ __launch_bounds__(512, 2) void gemm256(
    const unsigned short* __restrict__ A,
    const unsigned short* __restrict__ Bt,
    unsigned short* __restrict__ C,
    float* __restrict__ sums, float* __restrict__ sqs,
    int M, int N, int K)
{
    __shared__ unsigned short lds[2][32768];   // [buf][A:0..16384 | B:16384..32768]
    const int tid = threadIdx.x;
    const int lane = tid & 63, wid = tid >> 6;
    const int wrow = wid >> 2, wcol = wid & 3;
    const int nbn = N >> 8;
    const int bm = blockIdx.x / nbn, bn = blockIdx.x % nbn;
    const int NT = K >> 6;

    // staging: pre-swizzled global source, linear LDS dest (guide rule #21)
    const int srow = tid >> 3;
    const int skc  = (tid & 7) ^ (srow & 7);
    const unsigned short* Asrc = A + (size_t)(bm * 256 + srow) * K + skc * 8;
    const unsigned short* Bsrc = Bt + (size_t)(bn * 256 + srow) * K + skc * 8;

    #define STAGE_A(kt, b)                                                        \
        _Pragma("unroll")                                                         \
        for (int i_ = 0; i_ < 4; ++i_)                                            \
            __builtin_amdgcn_global_load_lds(                                     \
                (const __attribute__((address_space(1))) void*)(Asrc + (size_t)(i_ * 64) * K + (kt)), \
                (__attribute__((address_space(3))) void*)(&lds[b][tid * 8 + i_ * 4096]), 16, 0, 0);
    #define STAGE_B(kt, b)                                                        \
        _Pragma("unroll")                                                         \
        for (int i_ = 0; i_ < 4; ++i_)                                            \
            __builtin_amdgcn_global_load_lds(                                     \
                (const __attribute__((address_space(1))) void*)(Bsrc + (size_t)(i_ * 64) * K + (kt)), \
                (__attribute__((address_space(3))) void*)(&lds[b][16384 + tid * 8 + i_ * 4096]), 16, 0, 0);

    // fragment read offsets (swizzled; 2 lanes/bank-quad -> conflict-free)
    const int l15 = lane & 15, l7 = lane & 7, lhi = lane >> 4;
    const int xo0 = 8 * (lhi ^ l7);
    const int xo1 = 8 * ((lhi + 4) ^ l7);
    const int aRow = wrow * 128 + l15;
    const int bRow = wcol * 64 + l15;

    f32x4 acc[8][4];
    #pragma unroll
    for (int m = 0; m < 8; ++m)
        #pragma unroll
        for (int n = 0; n < 4; ++n) acc[m][n] = (f32x4){0.f, 0.f, 0.f, 0.f};

    STAGE_A(0, 0); STAGE_B(0, 0);
    STAGE_A(64, 1); STAGE_B(64, 1);
    asm volatile("s_waitcnt vmcnt(8)" ::: "memory");
    __builtin_amdgcn_s_barrier();

    for (int t = 0; t < NT; ++t) {
        const int cb = t & 1;
        const unsigned short* base = &lds[cb][0];
        const int ktp = (t + 2) << 6;
        const bool pf = (t + 2) < NT;

        short8 a[4][2], bfr[4][2];
        // ---- pA: read A-mh0 + all B; MFMA Q(0,*) x32 ----
        #pragma unroll
        for (int mf = 0; mf < 4; ++mf) {
            a[mf][0] = *(const short8*)(base + (aRow + mf * 16) * 64 + xo0);
            a[mf][1] = *(const short8*)(base + (aRow + mf * 16) * 64 + xo1);
        }
        #pragma unroll
        for (int nf = 0; nf < 4; ++nf) {
            bfr[nf][0] = *(const short8*)(base + 16384 + (bRow + nf * 16) * 64 + xo0);
            bfr[nf][1] = *(const short8*)(base + 16384 + (bRow + nf * 16) * 64 + xo1);
        }
        __builtin_amdgcn_s_setprio(1);
        #pragma unroll
        for (int mf = 0; mf < 4; ++mf)
            #pragma unroll
            for (int nf = 0; nf < 4; ++nf)
                #pragma unroll
                for (int kk = 0; kk < 2; ++kk)
                    acc[mf][nf] = __builtin_amdgcn_mfma_f32_16x16x32_bf16(
                        a[mf][kk], bfr[nf][kk], acc[mf][nf], 0, 0, 0);
        __builtin_amdgcn_s_setprio(0);
        __builtin_amdgcn_s_barrier();   // bar1: all waves consumed B region

        // ---- pB: stage B(t+2); read A-mh1; MFMA Q(1,*) x32 ----
        if (pf) { STAGE_B(ktp, cb); }
        #pragma unroll
        for (int mf = 0; mf < 4; ++mf) {
            a[mf][0] = *(const short8*)(base + (aRow + (mf + 4) * 16) * 64 + xo0);
            a[mf][1] = *(const short8*)(base + (aRow + (mf + 4) * 16) * 64 + xo1);
        }
        __builtin_amdgcn_s_setprio(1);
        #pragma unroll
        for (int mf = 0; mf < 4; ++mf)
            #pragma unroll
            for (int nf = 0; nf < 4; ++nf)
                #pragma unroll
                for (int kk = 0; kk < 2; ++kk)
                    acc[4 + mf][nf] = __builtin_amdgcn_mfma_f32_16x16x32_bf16(
                        a[mf][kk], bfr[nf][kk], acc[4 + mf][nf], 0, 0, 0);
        __builtin_amdgcn_s_setprio(0);
        __builtin_amdgcn_s_barrier();   // bar2: all waves consumed A region

        // ---- pC: stage A(t+2); counted wait for tile t+1; barrier ----
        if (t + 1 < NT) {
            if (pf) {
                STAGE_A(ktp, cb);
                asm volatile("s_waitcnt vmcnt(8)" ::: "memory");
            } else {
                asm volatile("s_waitcnt vmcnt(0)" ::: "memory");
            }
            __builtin_amdgcn_s_barrier();   // bar3: tile t+1 data visible to all
        }
    }

    // ---- epilogue: C write (bf16) + fused column sum/sumsq ----
    const int row0 = bm * 256 + wrow * 128 + lhi * 4;
    const int col0 = bn * 256 + wcol * 64 + l15;
    #pragma unroll
    for (int mf = 0; mf < 8; ++mf)
        #pragma unroll
        for (int nf = 0; nf < 4; ++nf)
            #pragma unroll
            for (int r = 0; r < 4; ++r)
                C[(size_t)(row0 + mf * 16 + r) * N + col0 + nf * 16] = f2bf(acc[mf][nf][r]);

    float s[4] = {0, 0, 0, 0}, q[4] = {0, 0, 0, 0};
    #pragma unroll
    for (int mf = 0; mf < 8; ++mf)
        #pragma unroll
        for (int nf = 0; nf < 4; ++nf)
            #pragma unroll
            for (int r = 0; r < 4; ++r) {
                float v = acc[mf][nf][r];
                s[nf] += v; q[nf] += v * v;
            }
    #pragma unroll
    for (int nf = 0; nf < 4; ++nf) {
        s[nf] += __shfl_xor(s[nf], 16); s[nf] += __shfl_xor(s[nf], 32);
        q[nf] += __shfl_xor(q[nf], 16); q[nf] += __shfl_xor(q[nf], 32);
    }
    if (lane < 16) {
        #pragma unroll
        for (int nf = 0; nf < 4; ++nf) {
            atomicAdd(&sums[col0 + nf * 16], s[nf]);
            atomicAdd(&sqs[col0 + nf * 16], q[nf]);
        }
    }
    #undef STAGE_A
    #undef STAGE_B
}

// ---------------------------------------------------------------------------
// GEMM2 fused: A = relu(BN1(z1)) computed in-flight during reg-staged A
// (BN1 coefficients derived from raw sums/sqs once per block into LDS);
// B via global_load_lds; fused column stats for BN2.  128x128 tile, m97 loop.
// ---------------------------------------------------------------------------
__global__ __launch_bounds__(256) void gemm2_fused(
    const unsigned short* __restrict__ z1,
    const unsigned short* __restrict__ Bt,
    unsigned short* __restrict__ C,
    const float* __restrict__ sums1, const float* __restrict__ sqs1,
    const float* __restrict__ g1, const float* __restrict__ be1,
    float* __restrict__ sums2, float* __restrict__ sqs2,
    int M, int N, int K, float invB)
{
    __shared__ unsigned short As[128 * 64];
    __shared__ unsigned short Bs[128 * 64];
    __shared__ float a1s[1024], b1s[1024];
    const int nbn = N >> 7;
    const int bm = blockIdx.x / nbn;
    const int bn = blockIdx.x % nbn;
    const int tid = threadIdx.x;
    const int lane = tid & 63;
    const int wave = tid >> 6;
    const int wr = (wave >> 1) << 6;
    const int wc = (wave & 1) << 6;

    // BN1 coefficients (folds bn_finalize): once per block
    for (int c = tid; c < K; c += 256) {
        float mu = sums1[c] * invB;
        float var = sqs1[c] * invB - mu * mu;
        float sc = g1[c] * rsqrtf(var + 1e-5f);
        a1s[c] = sc;
        b1s[c] = be1[c] - mu * sc;
    }
    __syncthreads();

    const int arow = bm * 128 + (tid >> 3);
    const int acol = (tid & 7) * 8;
    const unsigned short* Bb = Bt + (size_t)(bn * 128 + (tid >> 3)) * K + acol;
    unsigned short* Bsl = &Bs[tid * 8];

    f32x4 acc[4][4];
    #pragma unroll
    for (int m = 0; m < 4; ++m)
        #pragma unroll
        for (int n = 0; n < 4; ++n) acc[m][n] = (f32x4){0.f, 0.f, 0.f, 0.f};

    const int frow = lane & 15;
    const int fk = (lane >> 4) * 8;

    for (int kt = 0; kt < K; kt += 64) {
        // B staging: async global->LDS
        #pragma unroll
        for (int i = 0; i < 4; ++i)
            __builtin_amdgcn_global_load_lds(
                (const __attribute__((address_space(1))) void*)(Bb + (size_t)(i * 32) * K + kt),
                (__attribute__((address_space(3))) void*)(Bsl + i * 2048), 16, 0, 0);
        // A staging: reg-staged z1 with BN1+ReLU applied in flight
        u16x8 va[4];
        #pragma unroll
        for (int i = 0; i < 4; ++i)
            va[i] = *(const u16x8*)&z1[(size_t)(arow + i * 32) * K + kt + acol];
        const int c0 = kt + acol;
        float4 av0 = *(const float4*)&a1s[c0];
        float4 av1 = *(const float4*)&a1s[c0 + 4];
        float4 bv0 = *(const float4*)&b1s[c0];
        float4 bv1 = *(const float4*)&b1s[c0 + 4];
        float av[8] = {av0.x, av0.y, av0.z, av0.w, av1.x, av1.y, av1.z, av1.w};
        float bv[8] = {bv0.x, bv0.y, bv0.z, bv0.w, bv1.x, bv1.y, bv1.z, bv1.w};
        #pragma unroll
        for (int i = 0; i < 4; ++i) {
            short8 w;
            #pragma unroll
            for (int j = 0; j < 8; ++j)
                w[j] = (short)f2bf(fmaxf(av[j] * bf2f(va[i][j]) + bv[j], 0.f));
            *(short8*)&As[tid * 8 + i * 2048] = w;
        }
        __syncthreads();
        #pragma unroll
        for (int kk = 0; kk < 64; kk += 32) {
            short8 af[4], bfv[4];
            #pragma unroll
            for (int m = 0; m < 4; ++m)
                af[m] = *(const short8*)&As[(wr + m * 16 + frow) * 64 + kk + fk];
            #pragma unroll
            for (int n = 0; n < 4; ++n)
                bfv[n] = *(const short8*)&Bs[(wc + n * 16 + frow) * 64 + kk + fk];
            #pragma unroll
            for (int m = 0; m < 4; ++m)
                #pragma unroll
                for (int n = 0; n < 4; ++n)
                    acc[m][n] = __builtin_amdgcn_mfma_f32_16x16x32_bf16(
                        af[m], bfv[n], acc[m][n], 0, 0, 0);
        }
        __syncthreads();
    }

    const int row0 = bm * 128 + wr + (lane >> 4) * 4;
    const int col0 = bn * 128 + wc + (lane & 15);
    #pragma unroll
    for (int m = 0; m < 4; ++m)
        #pragma unroll
        for (int n = 0; n < 4; ++n)
            #pragma unroll
            for (int r = 0; r < 4; ++r)
                C[(size_t)(row0 + m * 16 + r) * N + col0 + n * 16] = f2bf(acc[m][n][r]);

    float s[4] = {0, 0, 0, 0}, q[4] = {0, 0, 0, 0};
    #pragma unroll
    for (int m = 0; m < 4; ++m)
        #pragma unroll
        for (int n = 0; n < 4; ++n)
            #pragma unroll
            for (int r = 0; r < 4; ++r) {
                float v = acc[m][n][r];
                s[n] += v; q[n] += v * v;
            }
    #pragma unroll
    for (int n = 0; n < 4; ++n) {
        s[n] += __shfl_xor(s[n], 16); s[n] += __shfl_xor(s[n], 32);
        q[n] += __shfl_xor(q[n], 16); q[n] += __shfl_xor(q[n], 32);
    }
    if (lane < 16) {
        #pragma unroll
        for (int n = 0; n < 4; ++n) {
            atomicAdd(&sums2[col0 + n * 16], s[n]);
            atomicAdd(&sqs2[col0 + n * 16], q[n]);
        }
    }
}

// ---------------------------------------------------------------------------
// Final: BN2 (coeffs from raw stats, folded) + ReLU + dot(W3) + b3 + fm
// -> sigmoid -> [1-p, p].  block (64,4): one wave per row.
// ---------------------------------------------------------------------------
__global__ __launch_bounds__(256) void final_k(
    const unsigned short* __restrict__ z2,
    const float* __restrict__ sums2, const float* __restrict__ sqs2,
    const float* __restrict__ g2, const float* __restrict__ be2,
    const float* __restrict__ W3, const float* __restrict__ b3,
    const float* __restrict__ fm, float* __restrict__ out, float invB)
{
    int row = blockIdx.x * 4 + threadIdx.y;
    int lane = threadIdx.x;
    int c = lane * 8;
    u16x8 u = *(const u16x8*)&z2[(size_t)row * 512 + c];
    float dot = 0.f;
    #pragma unroll
    for (int j = 0; j < 8; ++j) {
        float mu = sums2[c + j] * invB;
        float var = sqs2[c + j] * invB - mu * mu;
        float a = g2[c + j] * rsqrtf(var + 1e-5f);
        float b = be2[c + j] - mu * a;
        float x = a * bf2f(u[j]) + b;
        dot += fmaxf(x, 0.f) * W3[c + j];
    }
    #pragma unroll
    for (int off = 32; off; off >>= 1) dot += __shfl_xor(dot, off);
    if (lane == 0) {
        float logit = fm[row] + dot + b3[0];
        float p = 1.f / (1.f + expf(-logit));
        out[row * 2 + 0] = 1.f - p;
        out[row * 2 + 1] = p;
    }
}

// ---------------------------------------------------------------------------
extern "C" void kernel_launch(void* const* d_in, const int* in_sizes, int n_in,
                              void* d_out, int out_size, void* d_ws, size_t ws_size,
                              hipStream_t stream)
{
    const int*   cat  = (const int*)d_in[0];
    const float* cont = (const float*)d_in[1];
    const float* bias = (const float*)d_in[2];
    const float* t1c  = (const float*)d_in[3];
    const float* t2c  = (const float*)d_in[4];
    const float* t1x  = (const float*)d_in[5];
    const float* t2x  = (const float*)d_in[6];
    const float* W1   = (const float*)d_in[7];
    // d_in[8] = b1: cancels under training-mode BN
    const float* g1   = (const float*)d_in[9];
    const float* be1  = (const float*)d_in[10];
    const float* W2   = (const float*)d_in[11];
    // d_in[12] = b2: cancels
    const float* g2   = (const float*)d_in[13];
    const float* be2  = (const float*)d_in[14];
    const float* W3   = (const float*)d_in[15];
    const float* b3   = (const float*)d_in[16];
    float* out = (float*)d_out;

    const int B = 16384, K1 = 2496, H1 = 1024, H2 = 512;

    uint8_t* p = (uint8_t*)d_ws;
    auto carve = [&](size_t bytes) {
        uint8_t* r = p;
        p += (bytes + 255) & ~(size_t)255;
        return r;
    };
    unsigned short* deep = (unsigned short*)carve((size_t)B * K1 * 2);   // 81.8 MB
    unsigned short* w1t  = (unsigned short*)carve((size_t)H1 * K1 * 2);
    unsigned short* w2t  = (unsigned short*)carve((size_t)H2 * H1 * 2);
    unsigned short* z1   = (unsigned short*)carve((size_t)B * H1 * 2);
    unsigned short* z2   = (unsigned short*)carve((size_t)B * H2 * 2);
    float* fm    = (float*)carve((size_t)B * 4);
    float* stats = (float*)carve((size_t)(H1 * 2 + H2 * 2) * 4);
    float* sums1 = stats, *sqs1 = stats + H1, *sums2 = stats + 2 * H1, *sqs2 = stats + 2 * H1 + H2;

    hipMemsetAsync(stats, 0, (size_t)(H1 * 2 + H2 * 2) * 4, stream);

    // W1 + W2 transpose/cast in one launch: 2496 + 512 = 3008 blocks
    transpose_both<<<3008, dim3(32, 8), 0, stream>>>(W1, w1t, W2, w2t);

    embed_fm<<<B / 4, dim3(64, 4), 0, stream>>>(cat, cont, bias, t1c, t2c, t1x, t2x, deep, fm);

    // GEMM1: 256^2 tile, true counted-vmcnt pipeline, fused BN1 stats
    gemm256<<<(B / 256) * (H1 / 256), 512, 0, stream>>>(deep, w1t, z1, sums1, sqs1, B, H1, K1);

    // GEMM2: BN1-apply+ReLU fused into A staging, fused BN2 stats
    gemm2_fused<<<(B / 128) * (H2 / 128), 256, 0, stream>>>(
        z1, w2t, z2, sums1, sqs1, g1, be1, sums2, sqs2, B, H2, H1, 1.f / B);

    final_k<<<B / 4, dim3(64, 4), 0, stream>>>(z2, sums2, sqs2, g2, be2, W3, b3, fm, out, 1.f / B);
}